// Round 7
// baseline (246.242 us; speedup 1.0000x reference)
//
#include <hip/hip_runtime.h>
#include <hip/hip_bf16.h>
#include <stdint.h>

typedef __bf16 bf16;
typedef __bf16 bf16x8 __attribute__((ext_vector_type(8)));
typedef float f32x4 __attribute__((ext_vector_type(4)));

#define GAS __attribute__((address_space(1)))
#define LAS __attribute__((address_space(3)))

static constexpr int M = 4096;   // batch
static constexpr int N = 2048;   // 2C
static constexpr int K = 2048;   // 2C

static constexpr int BM = 128, BN = 256, BK = 64;
static constexpr int NT = K / BK;               // 32 K-tiles
static constexpr int A_ELE = BM * BK;           // 8192 bf16 = 16 KB per A buffer

// --- async global->LDS, 16B per lane, dest = wave-uniform base + lane*16 ---
__device__ __forceinline__ void gload_lds16(const bf16* gsrc, bf16* ldst) {
    __builtin_amdgcn_global_load_lds((const GAS void*)gsrc, (LAS void*)ldst, 16, 0, 0);
}

// --- merged prep: pack concat(x0,x1)->bf16  +  3x W[K][N]fp32 -> Wt[N][K]bf16 ---
__global__ __launch_bounds__(256) void prep_kernel(const float* __restrict__ x0,
                                                   const float* __restrict__ x1,
                                                   const float* __restrict__ W0,
                                                   const float* __restrict__ W1,
                                                   const float* __restrict__ W2,
                                                   bf16* __restrict__ A,
                                                   bf16* __restrict__ Wt0,
                                                   bf16* __restrict__ Wt1,
                                                   bf16* __restrict__ Wt2) {
    __shared__ bf16 tile[32][33];
    int bid = blockIdx.x;
    int tid = threadIdx.x;
    if (bid < 4096) {
        int idx = (bid * 256 + tid) * 8;
        int b = idx >> 11;
        int c = idx & 2047;
        const float* src = (c < 1024) ? (x0 + (size_t)b * 1024 + c)
                                      : (x1 + (size_t)b * 1024 + (c - 1024));
        float4 v0 = *reinterpret_cast<const float4*>(src);
        float4 v1 = *reinterpret_cast<const float4*>(src + 4);
        bf16x8 o;
        o[0] = (bf16)v0.x; o[1] = (bf16)v0.y; o[2] = (bf16)v0.z; o[3] = (bf16)v0.w;
        o[4] = (bf16)v1.x; o[5] = (bf16)v1.y; o[6] = (bf16)v1.z; o[7] = (bf16)v1.w;
        *reinterpret_cast<bf16x8*>(A + idx) = o;
    } else {
        int r = bid - 4096;
        int w = r >> 12;
        int t = r & 4095;
        const float* W  = (w == 0) ? W0  : (w == 1) ? W1  : W2;
        bf16*        Wt = (w == 0) ? Wt0 : (w == 1) ? Wt1 : Wt2;
        int n0 = (t & 63) * 32;
        int k0 = (t >> 6) * 32;
        int tx = tid & 31;
        int ty = tid >> 5;
        #pragma unroll
        for (int i = 0; i < 4; i++) {
            int k = ty + i * 8;
            tile[k][tx] = (bf16)W[(size_t)(k0 + k) * N + n0 + tx];
        }
        __syncthreads();
        #pragma unroll
        for (int i = 0; i < 4; i++) {
            int n = ty + i * 8;
            Wt[(size_t)(n0 + n) * K + k0 + tx] = tile[tx][n];   // Wt[n][k] = W[k][n]
        }
    }
}

__device__ __forceinline__ void read_a(const bf16* __restrict__ ba, int aoff, int slot, bf16x8 af[4]) {
    #pragma unroll
    for (int mi = 0; mi < 4; mi++)
        af[mi] = *reinterpret_cast<const bf16x8*>(ba + aoff + mi * 1024 + slot);
}

// B-frags direct from global (L2-resident Wt): 8 x 16B per wave per tile
__device__ __forceinline__ void load_b(const bf16* __restrict__ bB, int t, bf16x8 bv[8]) {
    const bf16* p = bB + (size_t)t * BK;
    #pragma unroll
    for (int ks = 0; ks < 2; ks++)
        #pragma unroll
        for (int ni = 0; ni < 4; ni++)
            bv[ks * 4 + ni] = *reinterpret_cast<const bf16x8*>(p + ks * 32 + (size_t)ni * 16 * K);
}

__device__ __forceinline__ void mfma_half(const bf16x8 af[4], const bf16x8 bv[8], int o, f32x4 acc[4][4]) {
    __builtin_amdgcn_s_setprio(1);
    #pragma unroll
    for (int mi = 0; mi < 4; mi++)
        #pragma unroll
        for (int ni = 0; ni < 4; ni++)
            acc[mi][ni] = __builtin_amdgcn_mfma_f32_16x16x32_bf16(af[mi], bv[o + ni], acc[mi][ni], 0, 0, 0);
    __builtin_amdgcn_s_setprio(0);
}

// --- 128x256-tile bf16 GEMM, 8 waves (2Mx4N, 64x64/wave), B-DIRECT variant:
//     A via gload_lds (swizzled, 4 rotating 16KB buffers, depth-2),
//     B via global->VGPR double bank (depth-1, L2-resident Wt),
//     per-tile: lgkm(4) -> vmcnt(12) -> MFMA ks0 -> lgkm(0) -> MFMA ks1 -> vmcnt(10) -> bar ---
template <bool OUT_BF16>
__global__ __launch_bounds__(512, 2) void gemmbd_kernel(const bf16* __restrict__ A,   // [M][K]
                                                        const bf16* __restrict__ Bt,  // [N][K]
                                                        void* __restrict__ Cout) {    // [M][N]
    __shared__ bf16 lds[4 * A_ELE];   // 64 KB, 4 rotating A buffers

    int bid = blockIdx.x;
    int cpx = gridDim.x >> 3;
    int swz = (bid & 7) * cpx + (bid >> 3);
    int tm = swz >> 3;                           // 0..31
    int tn = swz & 7;                            // 0..7

    int tid  = threadIdx.x;
    int wave = tid >> 6;        // 0..7
    int lane = tid & 63;
    int wr = wave >> 2;         // 0..1  (M half)
    int wc = wave & 3;          // 0..3  (N quarter)
    int fr = lane & 15;
    int fb = lane >> 4;

    // A staging: wave stages rows {w*8..w*8+7} and {64+w*8..} of the 128-row A tile
    int srow = wave * 8 + (lane >> 3);
    int scol = ((lane & 7) ^ (lane >> 3)) * 8;            // T2 pre-swizzled source col
    const bf16* aS = A + (size_t)(tm * BM + srow) * K + scol;
    int sdst = wave * 512;

    // B direct-load base: per-lane row (wc*64 + ni*16 + fr), col chunk fb*8
    const bf16* bB = Bt + (size_t)(tn * BN + wc * 64 + fr) * K + fb * 8;

    // A frag read geometry (swizzled)
    int aoff  = (wr * 64 + fr) * 64;
    int slot0 = ((fb) ^ (fr & 7)) * 8;
    int slot1 = ((4 | fb) ^ (fr & 7)) * 8;

    f32x4 acc[4][4] = {};
    bf16x8 af0[4], af1[4], bvA[8], bvB[8];

    auto STAGE_A = [&](int bi, int t) {                   // 2 gloads
        bf16* ba = (bf16*)lds + bi * A_ELE;
        const bf16* a = aS + t * BK;
        gload_lds16(a,          ba + sdst);
        gload_lds16(a + 64 * K, ba + sdst + 4096);
    };

    auto TILE = [&](int t, bf16x8 (&bvC)[8], bf16x8 (&bvN)[8]) {
        const bf16* ba = (const bf16*)lds + (t & 3) * A_ELE;
        load_b(bB, t + 1, bvN);                            // 8 vmem
        __builtin_amdgcn_sched_barrier(0);
        read_a(ba, aoff, slot0, af0);                      // 4 ds
        __builtin_amdgcn_sched_barrier(0);
        read_a(ba, aoff, slot1, af1);                      // 4 ds
        __builtin_amdgcn_sched_barrier(0);
        STAGE_A((t + 2) & 3, t + 2);                       // 2 vmem
        __builtin_amdgcn_sched_barrier(0);
        asm volatile("s_waitcnt lgkmcnt(4)" ::: "memory");  // af0 resident
        asm volatile("s_waitcnt vmcnt(12)" ::: "memory");   // B(t) resident
        __builtin_amdgcn_sched_barrier(0);
        mfma_half(af0, bvC, 0, acc);
        asm volatile("s_waitcnt lgkmcnt(0)" ::: "memory");  // af1 resident
        __builtin_amdgcn_sched_barrier(0);
        mfma_half(af1, bvC, 4, acc);
        asm volatile("s_waitcnt vmcnt(10)" ::: "memory");   // A(t+1) staged (cross-wave -> barrier)
        __builtin_amdgcn_s_barrier();
    };

    // ---- prologue: B(0) -> bvA; A(0),A(1) staged ----
    load_b(bB, 0, bvA);
    __builtin_amdgcn_sched_barrier(0);
    STAGE_A(0, 0);
    STAGE_A(1, 1);
    __builtin_amdgcn_sched_barrier(0);
    asm volatile("s_waitcnt vmcnt(2)" ::: "memory");        // B(0), A(0) resident; A(1) in flight
    __builtin_amdgcn_s_barrier();

    // ---- main loop: t = 0..29, banks alternate statically ----
    for (int i = 0; i < 15; ++i) {
        TILE(2 * i,     bvA, bvB);
        TILE(2 * i + 1, bvB, bvA);
    }
    // ---- t = 30: cur bvA, load B(31) -> bvB, no staging ----
    {
        const bf16* ba = (const bf16*)lds + (30 & 3) * A_ELE;
        load_b(bB, 31, bvB);
        __builtin_amdgcn_sched_barrier(0);
        read_a(ba, aoff, slot0, af0);
        __builtin_amdgcn_sched_barrier(0);
        read_a(ba, aoff, slot1, af1);
        __builtin_amdgcn_sched_barrier(0);
        asm volatile("s_waitcnt lgkmcnt(4)" ::: "memory");
        asm volatile("s_waitcnt vmcnt(10)" ::: "memory");   // B(30) resident
        __builtin_amdgcn_sched_barrier(0);
        mfma_half(af0, bvA, 0, acc);
        asm volatile("s_waitcnt lgkmcnt(0)" ::: "memory");
        __builtin_amdgcn_sched_barrier(0);
        mfma_half(af1, bvA, 4, acc);
        asm volatile("s_waitcnt vmcnt(8)" ::: "memory");    // A(31) staged
        __builtin_amdgcn_s_barrier();
    }
    // ---- t = 31: cur bvB ----
    {
        const bf16* ba = (const bf16*)lds + (31 & 3) * A_ELE;
        read_a(ba, aoff, slot0, af0);
        __builtin_amdgcn_sched_barrier(0);
        read_a(ba, aoff, slot1, af1);
        __builtin_amdgcn_sched_barrier(0);
        asm volatile("s_waitcnt lgkmcnt(4)" ::: "memory");
        asm volatile("s_waitcnt vmcnt(0)" ::: "memory");    // B(31) resident
        __builtin_amdgcn_sched_barrier(0);
        mfma_half(af0, bvB, 0, acc);
        asm volatile("s_waitcnt lgkmcnt(0)" ::: "memory");
        __builtin_amdgcn_sched_barrier(0);
        mfma_half(af1, bvB, 4, acc);
    }

    // ---- epilogue: C/D layout col = lane&15, row = (lane>>4)*4 + reg ----
    int row0 = tm * BM + wr * 64 + (lane >> 4) * 4;
    int col0 = tn * BN + wc * 64 + (lane & 15);
    if constexpr (OUT_BF16) {
        bf16* C = (bf16*)Cout;
        #pragma unroll
        for (int mi = 0; mi < 4; mi++)
            #pragma unroll
            for (int r = 0; r < 4; r++) {
                size_t base = (size_t)(row0 + mi * 16 + r) * N + col0;
                #pragma unroll
                for (int ni = 0; ni < 4; ni++)
                    C[base + ni * 16] = (bf16)acc[mi][ni][r];
            }
    } else {
        float* C = (float*)Cout;
        #pragma unroll
        for (int mi = 0; mi < 4; mi++)
            #pragma unroll
            for (int r = 0; r < 4; r++) {
                size_t base = (size_t)(row0 + mi * 16 + r) * N + col0;
                #pragma unroll
                for (int ni = 0; ni < 4; ni++)
                    C[base + ni * 16] = acc[mi][ni][r];
            }
    }
}

extern "C" void kernel_launch(void* const* d_in, const int* in_sizes, int n_in,
                              void* d_out, int out_size, void* d_ws, size_t ws_size,
                              hipStream_t stream) {
    const float* x0 = (const float*)d_in[0];
    const float* x1 = (const float*)d_in[1];
    const float* W0 = (const float*)d_in[2];
    const float* W1 = (const float*)d_in[3];
    const float* W2 = (const float*)d_in[4];

    char* ws = (char*)d_ws;
    const size_t MB = 1024 * 1024;
    bf16* Wt0 = (bf16*)(ws + 0 * MB);
    bf16* Wt1 = (bf16*)(ws + 8 * MB);
    bf16* Wt2 = (bf16*)(ws + 16 * MB);

    bf16 *Apk, *z1, *z2;
    if (ws_size >= 56 * MB) {
        Apk = (bf16*)(ws + 24 * MB);
        z1  = (bf16*)(ws + 40 * MB);
        z2  = Apk;                               // Apk dead after GEMM1
    } else {
        Apk = (bf16*)d_out;
        z1  = (bf16*)d_out + (size_t)M * K;      // second half of d_out
        z2  = (bf16*)(ws + 24 * MB);
    }

    prep_kernel<<<4096 + 3 * 4096, 256, 0, stream>>>(x0, x1, W0, W1, W2, Apk, Wt0, Wt1, Wt2);

    constexpr int grid = (M / BM) * (N / BN);    // 32 * 8 = 256
    gemmbd_kernel<true ><<<grid, 512, 0, stream>>>(Apk, Wt0, z1);
    gemmbd_kernel<true ><<<grid, 512, 0, stream>>>(z1,  Wt1, z2);
    gemmbd_kernel<false><<<grid, 512, 0, stream>>>(z2,  Wt2, (float*)d_out);
}

// Round 8
// 101.148 us; speedup vs baseline: 2.4345x; 2.4345x over previous
//
#include <hip/hip_runtime.h>
#include <hip/hip_bf16.h>
#include <stdint.h>

typedef __bf16 bf16;
typedef __bf16 bf16x8 __attribute__((ext_vector_type(8)));
typedef float f32x4 __attribute__((ext_vector_type(4)));

#define GAS __attribute__((address_space(1)))
#define LAS __attribute__((address_space(3)))

static constexpr int M = 4096;   // batch
static constexpr int N = 2048;   // 2C
static constexpr int K = 2048;   // 2C

// ---- X-GEMM (G3) geometry: 128x256, 8 waves ----
static constexpr int BM = 128, BN = 256, BK = 64;
static constexpr int NT = K / BK;               // 32 K-tiles
static constexpr int A_ELE = BM * BK;           // 16 KB
static constexpr int B_ELE = BN * BK;           // 32 KB
static constexpr int BUF_ELE = A_ELE + B_ELE;   // 48 KB; x3 = 144 KB

// ---- weight-GEMM (G1/G2) geometry: 64x128, 4 waves, 2 blocks/CU ----
static constexpr int WA_ELE = 64 * BK;              // 8 KB
static constexpr int WB_ELE = 128 * BK;             // 16 KB
static constexpr int WBUF_ELE = WA_ELE + WB_ELE;    // 24 KB; x3 = 72 KB

// --- async global->LDS, 16B per lane, dest = wave-uniform base + lane*16 ---
__device__ __forceinline__ void gload_lds16(const bf16* gsrc, bf16* ldst) {
    __builtin_amdgcn_global_load_lds((const GAS void*)gsrc, (LAS void*)ldst, 16, 0, 0);
}

// --- prep: Xpk = concat(x0,x1) bf16; W0pk = pack(W0); W1t,W2t = transpose+pack ---
__global__ __launch_bounds__(256) void prep_kernel(const float* __restrict__ x0,
                                                   const float* __restrict__ x1,
                                                   const float* __restrict__ W0,
                                                   const float* __restrict__ W1,
                                                   const float* __restrict__ W2,
                                                   bf16* __restrict__ Xpk,
                                                   bf16* __restrict__ W0pk,
                                                   bf16* __restrict__ W1t,
                                                   bf16* __restrict__ W2t) {
    __shared__ bf16 tile[32][33];
    int bid = blockIdx.x;
    int tid = threadIdx.x;
    if (bid < 4096) {
        // Xpk: 8 elems/thread; 8-chunks never straddle the 1024 seam
        int idx = (bid * 256 + tid) * 8;
        int b = idx >> 11;
        int c = idx & 2047;
        const float* src = (c < 1024) ? (x0 + (size_t)b * 1024 + c)
                                      : (x1 + (size_t)b * 1024 + (c - 1024));
        float4 v0 = *reinterpret_cast<const float4*>(src);
        float4 v1 = *reinterpret_cast<const float4*>(src + 4);
        bf16x8 o;
        o[0] = (bf16)v0.x; o[1] = (bf16)v0.y; o[2] = (bf16)v0.z; o[3] = (bf16)v0.w;
        o[4] = (bf16)v1.x; o[5] = (bf16)v1.y; o[6] = (bf16)v1.z; o[7] = (bf16)v1.w;
        *reinterpret_cast<bf16x8*>(Xpk + idx) = o;
    } else if (bid < 6144) {
        // W0pk: straight pack, row-major
        int idx = ((bid - 4096) * 256 + tid) * 8;
        float4 v0 = *reinterpret_cast<const float4*>(W0 + idx);
        float4 v1 = *reinterpret_cast<const float4*>(W0 + idx + 4);
        bf16x8 o;
        o[0] = (bf16)v0.x; o[1] = (bf16)v0.y; o[2] = (bf16)v0.z; o[3] = (bf16)v0.w;
        o[4] = (bf16)v1.x; o[5] = (bf16)v1.y; o[6] = (bf16)v1.z; o[7] = (bf16)v1.w;
        *reinterpret_cast<bf16x8*>(W0pk + idx) = o;
    } else {
        // W1t / W2t: 32x32 LDS-tiled transpose
        int r = bid - 6144;
        int w = r >> 12;                 // 0: W1, 1: W2
        int t = r & 4095;
        const float* W  = (w == 0) ? W1  : W2;
        bf16*        Wt = (w == 0) ? W1t : W2t;
        int n0 = (t & 63) * 32;
        int k0 = (t >> 6) * 32;
        int tx = tid & 31;
        int ty = tid >> 5;
        #pragma unroll
        for (int i = 0; i < 4; i++) {
            int k = ty + i * 8;
            tile[k][tx] = (bf16)W[(size_t)(k0 + k) * N + n0 + tx];
        }
        __syncthreads();
        #pragma unroll
        for (int i = 0; i < 4; i++) {
            int n = ty + i * 8;
            Wt[(size_t)(n0 + n) * K + k0 + tx] = tile[tx][n];   // Wt[n][k] = W[k][n]
        }
    }
}

// ================= G3: X-GEMM (R5 structure, unchanged) =================
__device__ __forceinline__ void read_frags(const bf16* __restrict__ ba, const bf16* __restrict__ bb,
                                           int aoff, int boff, int slot,
                                           bf16x8 af[4], bf16x8 bv[4]) {
    #pragma unroll
    for (int mi = 0; mi < 4; mi++)
        af[mi] = *reinterpret_cast<const bf16x8*>(ba + aoff + mi * 1024 + slot);
    #pragma unroll
    for (int ni = 0; ni < 4; ni++)
        bv[ni] = *reinterpret_cast<const bf16x8*>(bb + boff + ni * 1024 + slot);
}

__device__ __forceinline__ void do_mfma16(const bf16x8 af[4], const bf16x8 bv[4], f32x4 acc[4][4]) {
    __builtin_amdgcn_s_setprio(1);
    #pragma unroll
    for (int mi = 0; mi < 4; mi++)
        #pragma unroll
        for (int ni = 0; ni < 4; ni++)
            acc[mi][ni] = __builtin_amdgcn_mfma_f32_16x16x32_bf16(af[mi], bv[ni], acc[mi][ni], 0, 0, 0);
    __builtin_amdgcn_s_setprio(0);
}

__global__ __launch_bounds__(512, 2) void gemmx_kernel(const bf16* __restrict__ A,   // [4096][K]
                                                       const bf16* __restrict__ Bt,  // [N][K]
                                                       float* __restrict__ Cout) {   // [4096][N] fp32
    __shared__ bf16 lds[3 * BUF_ELE];   // 144 KB

    int bid = blockIdx.x;
    int cpx = gridDim.x >> 3;
    int swz = (bid & 7) * cpx + (bid >> 3);
    int tm = swz >> 3;                           // 0..31
    int tn = swz & 7;                            // 0..7

    int tid  = threadIdx.x;
    int wave = tid >> 6;
    int lane = tid & 63;
    int wr = wave >> 2;
    int wc = wave & 3;
    int fr = lane & 15;
    int fb = lane >> 4;

    int srow = wave * 8 + (lane >> 3);
    int scol = ((lane & 7) ^ (lane >> 3)) * 8;
    const bf16* aS = A  + (size_t)(tm * BM + srow) * K + scol;
    const bf16* bS = Bt + (size_t)(tn * BN + srow) * K + scol;
    int sdst = wave * 512;

    int aoff  = (wr * 64 + fr) * 64;
    int boff  = (wc * 64 + fr) * 64;
    int slot0 = ((fb) ^ (fr & 7)) * 8;
    int slot1 = ((4 | fb) ^ (fr & 7)) * 8;

    f32x4 acc[4][4] = {};

    auto STAGE = [&](int bi, int t) {
        bf16* ba = (bf16*)lds + bi * BUF_ELE;
        bf16* bb = ba + A_ELE;
        const bf16* a = aS + t * BK;
        const bf16* b = bS + t * BK;
        gload_lds16(a,           ba + sdst);
        gload_lds16(a + 64 * K,  ba + sdst + 4096);
        gload_lds16(b,           bb + sdst);
        gload_lds16(b + 64 * K,  bb + sdst + 4096);
        gload_lds16(b + 128 * K, bb + sdst + 8192);
        gload_lds16(b + 192 * K, bb + sdst + 12288);
    };

    STAGE(0, 0);
    STAGE(1, 1);
    asm volatile("s_waitcnt vmcnt(6)" ::: "memory");
    __builtin_amdgcn_s_barrier();

    bf16x8 af0[4], bv0[4], af1[4], bv1[4];
    int cur = 0;
    for (int t = 0; t < NT - 2; ++t) {
        const bf16* ba = (const bf16*)lds + cur * BUF_ELE;
        const bf16* bb = ba + A_ELE;
        int sb = cur + 2; if (sb >= 3) sb -= 3;

        read_frags(ba, bb, aoff, boff, slot0, af0, bv0);
        read_frags(ba, bb, aoff, boff, slot1, af1, bv1);
        STAGE(sb, t + 2);
        asm volatile("s_waitcnt lgkmcnt(8)" ::: "memory");
        __builtin_amdgcn_sched_barrier(0);
        do_mfma16(af0, bv0, acc);
        asm volatile("s_waitcnt lgkmcnt(0)" ::: "memory");
        __builtin_amdgcn_sched_barrier(0);
        do_mfma16(af1, bv1, acc);
        asm volatile("s_waitcnt vmcnt(6)" ::: "memory");
        __builtin_amdgcn_s_barrier();
        cur = cur + 1; if (cur >= 3) cur -= 3;
    }
    {
        const bf16* ba = (const bf16*)lds + cur * BUF_ELE;
        const bf16* bb = ba + A_ELE;
        read_frags(ba, bb, aoff, boff, slot0, af0, bv0);
        read_frags(ba, bb, aoff, boff, slot1, af1, bv1);
        asm volatile("s_waitcnt lgkmcnt(8)" ::: "memory");
        __builtin_amdgcn_sched_barrier(0);
        do_mfma16(af0, bv0, acc);
        asm volatile("s_waitcnt lgkmcnt(0)" ::: "memory");
        __builtin_amdgcn_sched_barrier(0);
        do_mfma16(af1, bv1, acc);
        asm volatile("s_waitcnt vmcnt(0)" ::: "memory");
        __builtin_amdgcn_s_barrier();
        cur = cur + 1; if (cur >= 3) cur -= 3;
    }
    {
        const bf16* ba = (const bf16*)lds + cur * BUF_ELE;
        const bf16* bb = ba + A_ELE;
        read_frags(ba, bb, aoff, boff, slot0, af0, bv0);
        read_frags(ba, bb, aoff, boff, slot1, af1, bv1);
        asm volatile("s_waitcnt lgkmcnt(8)" ::: "memory");
        __builtin_amdgcn_sched_barrier(0);
        do_mfma16(af0, bv0, acc);
        asm volatile("s_waitcnt lgkmcnt(0)" ::: "memory");
        __builtin_amdgcn_sched_barrier(0);
        do_mfma16(af1, bv1, acc);
    }

    int row0 = tm * BM + wr * 64 + (lane >> 4) * 4;
    int col0 = tn * BN + wc * 64 + (lane & 15);
    #pragma unroll
    for (int mi = 0; mi < 4; mi++)
        #pragma unroll
        for (int r = 0; r < 4; r++) {
            size_t base = (size_t)(row0 + mi * 16 + r) * N + col0;
            #pragma unroll
            for (int ni = 0; ni < 4; ni++)
                Cout[base + ni * 16] = acc[mi][ni][r];
        }
}

// ============ G1/G2: weight GEMM 2048x2048x2048, 64x128 tile, 4 waves, 2 blk/CU ============
__global__ __launch_bounds__(256, 2) void gemmw_kernel(const bf16* __restrict__ A,   // [2048][K]
                                                       const bf16* __restrict__ Bt,  // [2048][K]
                                                       bf16* __restrict__ C) {       // [2048][2048] bf16
    __shared__ bf16 lds[3 * WBUF_ELE];   // 72 KB -> 2 blocks/CU

    int bid = blockIdx.x;
    int cpx = gridDim.x >> 3;                    // 64
    int swz = (bid & 7) * cpx + (bid >> 3);      // 512 % 8 == 0, bijective
    int tm = swz >> 4;                           // 0..31  (ntn = 2048/128 = 16)
    int tn = swz & 15;

    int tid  = threadIdx.x;
    int wave = tid >> 6;        // 0..3
    int lane = tid & 63;
    int wr = wave >> 1;         // 0..1  (M half, 32 rows)
    int wc = wave & 1;          // 0..1  (N half, 64 cols)
    int fr = lane & 15;
    int fb = lane >> 4;

    // staging: 256 threads cover 32 rows x 64 cols per gload (4 KB)
    int srow = tid >> 3;                                   // 0..31
    int scol = ((tid & 7) ^ (srow & 7)) * 8;               // T2 pre-swizzle
    const bf16* aS = A  + (size_t)(tm * 64  + srow) * K + scol;
    const bf16* bS = Bt + (size_t)(tn * 128 + srow) * K + scol;
    int sdst = wave * 512;

    int aoff  = (wr * 32 + fr) * 64;
    int boff  = (wc * 64 + fr) * 64;
    int slot0 = ((fb) ^ (fr & 7)) * 8;
    int slot1 = ((4 | fb) ^ (fr & 7)) * 8;

    f32x4 acc[2][4] = {};

    auto STAGE = [&](int bi, int t) {                       // 6 loads: A 2 chunks, B 4 chunks
        bf16* ba = (bf16*)lds + bi * WBUF_ELE;
        bf16* bb = ba + WA_ELE;
        const bf16* a = aS + t * BK;
        const bf16* b = bS + t * BK;
        gload_lds16(a,          ba + sdst);
        gload_lds16(a + 32 * K, ba + sdst + 2048);
        #pragma unroll
        for (int c = 0; c < 4; c++)
            gload_lds16(b + (size_t)c * 32 * K, bb + sdst + c * 2048);
    };

    auto READ = [&](const bf16* ba, const bf16* bb, int slot, bf16x8 af[2], bf16x8 bv[4]) {
        af[0] = *reinterpret_cast<const bf16x8*>(ba + aoff + slot);
        af[1] = *reinterpret_cast<const bf16x8*>(ba + aoff + 1024 + slot);
        #pragma unroll
        for (int ni = 0; ni < 4; ni++)
            bv[ni] = *reinterpret_cast<const bf16x8*>(bb + boff + ni * 1024 + slot);
    };

    auto MFMA8 = [&](const bf16x8 af[2], const bf16x8 bv[4]) {
        __builtin_amdgcn_s_setprio(1);
        #pragma unroll
        for (int mi = 0; mi < 2; mi++)
            #pragma unroll
            for (int ni = 0; ni < 4; ni++)
                acc[mi][ni] = __builtin_amdgcn_mfma_f32_16x16x32_bf16(af[mi], bv[ni], acc[mi][ni], 0, 0, 0);
        __builtin_amdgcn_s_setprio(0);
    };

    STAGE(0, 0);
    STAGE(1, 1);
    asm volatile("s_waitcnt vmcnt(6)" ::: "memory");
    __builtin_amdgcn_s_barrier();

    bf16x8 af0[2], bv0[4], af1[2], bv1[4];
    int cur = 0;
    for (int t = 0; t < NT - 2; ++t) {
        const bf16* ba = (const bf16*)lds + cur * WBUF_ELE;
        const bf16* bb = ba + WA_ELE;
        int sb = cur + 2; if (sb >= 3) sb -= 3;

        READ(ba, bb, slot0, af0, bv0);                     // 6 ds_read
        READ(ba, bb, slot1, af1, bv1);                     // 6 ds_read
        STAGE(sb, t + 2);                                  // 6 gloads
        asm volatile("s_waitcnt lgkmcnt(6)" ::: "memory"); // ks0 resident
        __builtin_amdgcn_sched_barrier(0);
        MFMA8(af0, bv0);
        asm volatile("s_waitcnt lgkmcnt(0)" ::: "memory");
        __builtin_amdgcn_sched_barrier(0);
        MFMA8(af1, bv1);
        asm volatile("s_waitcnt vmcnt(6)" ::: "memory");   // t+1 resident; t+2 in flight
        __builtin_amdgcn_s_barrier();
        cur = cur + 1; if (cur >= 3) cur -= 3;
    }
    {
        const bf16* ba = (const bf16*)lds + cur * WBUF_ELE;
        const bf16* bb = ba + WA_ELE;
        READ(ba, bb, slot0, af0, bv0);
        READ(ba, bb, slot1, af1, bv1);
        asm volatile("s_waitcnt lgkmcnt(6)" ::: "memory");
        __builtin_amdgcn_sched_barrier(0);
        MFMA8(af0, bv0);
        asm volatile("s_waitcnt lgkmcnt(0)" ::: "memory");
        __builtin_amdgcn_sched_barrier(0);
        MFMA8(af1, bv1);
        asm volatile("s_waitcnt vmcnt(0)" ::: "memory");
        __builtin_amdgcn_s_barrier();
        cur = cur + 1; if (cur >= 3) cur -= 3;
    }
    {
        const bf16* ba = (const bf16*)lds + cur * WBUF_ELE;
        const bf16* bb = ba + WA_ELE;
        READ(ba, bb, slot0, af0, bv0);
        READ(ba, bb, slot1, af1, bv1);
        asm volatile("s_waitcnt lgkmcnt(6)" ::: "memory");
        __builtin_amdgcn_sched_barrier(0);
        MFMA8(af0, bv0);
        asm volatile("s_waitcnt lgkmcnt(0)" ::: "memory");
        __builtin_amdgcn_sched_barrier(0);
        MFMA8(af1, bv1);
    }

    int row0 = tm * 64 + wr * 32 + (lane >> 4) * 4;
    int col0 = tn * 128 + wc * 64 + fr;
    #pragma unroll
    for (int mi = 0; mi < 2; mi++)
        #pragma unroll
        for (int r = 0; r < 4; r++) {
            size_t base = (size_t)(row0 + mi * 16 + r) * 2048 + col0;
            #pragma unroll
            for (int ni = 0; ni < 4; ni++)
                C[base + ni * 16] = (bf16)acc[mi][ni][r];
        }
}

extern "C" void kernel_launch(void* const* d_in, const int* in_sizes, int n_in,
                              void* d_out, int out_size, void* d_ws, size_t ws_size,
                              hipStream_t stream) {
    const float* x0 = (const float*)d_in[0];
    const float* x1 = (const float*)d_in[1];
    const float* W0 = (const float*)d_in[2];
    const float* W1 = (const float*)d_in[3];
    const float* W2 = (const float*)d_in[4];

    // out = X @ W0 @ W1 @ W2  ==  X @ (W0@W1@W2)   [associativity: 103 -> 68.7 GFLOP]
    // ws (40 MB): Xpk@0 (16M), W1t@16M (8M, dead after G1, reused for W012t),
    //             W2t@24M (8M), W01@32M (8M).  W0pk lives in d_out (dead before G3 writes).
    char* ws = (char*)d_ws;
    const size_t MB = 1024 * 1024;
    bf16* Xpk    = (bf16*)(ws + 0 * MB);
    bf16* W1t    = (bf16*)(ws + 16 * MB);
    bf16* W012t  = (bf16*)(ws + 16 * MB);    // overlays W1t (dead after G1)
    bf16* W2t    = (bf16*)(ws + 24 * MB);
    bf16* W01    = (bf16*)(ws + 32 * MB);
    bf16* W0pk   = (bf16*)d_out;             // 8 MB of the 32 MB output buffer

    prep_kernel<<<4096 + 2048 + 2 * 4096, 256, 0, stream>>>(x0, x1, W0, W1, W2,
                                                            Xpk, W0pk, W1t, W2t);

    // G1: W01 = W0 @ W1            C[m][n] = sum_k W0pk[m][k] * W1t[n][k]
    gemmw_kernel<<<(2048 / 64) * (2048 / 128), 256, 0, stream>>>(W0pk, W1t, W01);
    // G2: W012t = W2^T @ W01^T     C[a][b] = sum_k W2t[a][k] * W01[b][k] = (W01@W2)^T
    gemmw_kernel<<<(2048 / 64) * (2048 / 128), 256, 0, stream>>>(W2t, W01, W012t);
    // G3: out = X @ W012           C[m][n] = sum_k Xpk[m][k] * W012t[n][k]
    gemmx_kernel<<<(M / BM) * (N / BN), 512, 0, stream>>>(Xpk, W012t, (float*)d_out);
}